// Round 2
// baseline (310.554 us; speedup 1.0000x reference)
//
#include <hip/hip_runtime.h>

// GenerateNodes: out[n,t,o,k] = sum_c mix[n,t,c] * W[k,o,c] + b[k,o]
// mix = concat(x [16384,3200], seeds [16384,15])  -> GEMM M=16384, K=3215, Ncol=60
// bf16 MFMA 16x16x32. B prepacked to fragment order in static __device__ mem.
// K split 8 ways: 4 waves/block x 2 blocks per 16-row group (2048 blocks,
// ~24 waves/CU at launch_bounds(256,6)). Partials land in d_ws (the 800 MiB
// harness poison fill is unconditional -- using d_ws is free), combined by a
// tiny epilogue kernel that adds bias. x loads are nontemporal (zero reuse;
// keeps Wb hot in L2) with explicit depth-2 prefetch rotation.

#define NROWS    16384
#define CIN      3200
#define SEED_K   15
#define LIN_IN   3215
#define NCOL     60
#define KB_MAIN  100          // 3200 / 32
#define KB_TOT   101          // + tail block covering the 15 seed channels
#define WB_ELEMS (KB_TOT * 4 * 64 * 8)   // 206848 ushorts
#define PART_N   (NROWS * NCOL)          // 983040 floats per K-half partial

typedef __attribute__((ext_vector_type(8))) __bf16 bf16x8;
typedef __attribute__((ext_vector_type(4))) float f32x4;
typedef __attribute__((ext_vector_type(8))) unsigned short ushort8;

__device__ unsigned short Wb_g[WB_ELEMS];
__device__ __align__(16) float bias_g[64];

__device__ inline unsigned short f2bf_rne(float f) {
    unsigned int u = __builtin_bit_cast(unsigned int, f);
    u += 0x7fffu + ((u >> 16) & 1u);
    return (unsigned short)(u >> 16);
}

__device__ inline bf16x8 to_bf16x8(f32x4 a0, f32x4 a1) {
    ushort8 u;
    u[0] = f2bf_rne(a0[0]); u[1] = f2bf_rne(a0[1]);
    u[2] = f2bf_rne(a0[2]); u[3] = f2bf_rne(a0[3]);
    u[4] = f2bf_rne(a1[0]); u[5] = f2bf_rne(a1[1]);
    u[6] = f2bf_rne(a1[2]); u[7] = f2bf_rne(a1[3]);
    return __builtin_bit_cast(bf16x8, u);
}

// Pack W[20,3,3215] fp32 into bf16 B-fragment order:
// Wb[kb][nt][lane][jj] = B[k = kb*32 + (lane>>4)*8 + jj][n = nt*16 + (lane&15)]
// where B[c][j] = W[j%20][j/20][c]; zero-pad k>=3215 and n>=60.
// Also stages the transposed bias vector bias_g[j] = b[j%20][j/20].
__global__ void prep_B(const float* __restrict__ W, const float* __restrict__ b) {
    int idx = blockIdx.x * blockDim.x + threadIdx.x;
    if (idx >= WB_ELEMS) return;
    if (idx < 64) bias_g[idx] = (idx < NCOL) ? b[(idx % 20) * 3 + (idx / 20)] : 0.f;
    int jj   = idx & 7;
    int lane = (idx >> 3) & 63;
    int nt   = (idx >> 9) & 3;
    int kb   = idx >> 11;
    int k = kb * 32 + (lane >> 4) * 8 + jj;
    int n = nt * 16 + (lane & 15);
    float v = 0.0f;
    if (k < LIN_IN && n < NCOL) {
        int o = n / 20, kn = n % 20;
        v = W[(kn * 3 + o) * LIN_IN + k];
    }
    Wb_g[idx] = f2bf_rne(v);
}

__global__ __launch_bounds__(256, 6) void gen_nodes_part(
    const float* __restrict__ x, const float* __restrict__ seeds,
    float* __restrict__ part) {
    const int lane = threadIdx.x & 63;
    const int wave = threadIdx.x >> 6;
    const int quad = lane >> 4;
    const int l15  = lane & 15;
    const int rg   = blockIdx.x >> 1;       // 16-row group, 0..1023
    const int kh   = blockIdx.x & 1;        // K half, 0..1
    const int row_base = rg * 16;
    const int arow = row_base + l15;

    const float* xrow = x + (size_t)arow * CIN + quad * 8;

    f32x4 acc[4];
#pragma unroll
    for (int i = 0; i < 4; ++i) acc[i] = (f32x4){0.f, 0.f, 0.f, 0.f};

    // Interleaved K: this wave does kb = kh*50 + wave, +4, +8, ... (< kh*50+50).
    // 13 iters for waves 0-1, 12 for waves 2-3. Depth-2 rotated prefetch.
    const int kend = kh * 50 + 50;
    int kb = kh * 50 + wave;
    const f32x4* ap = (const f32x4*)(xrow + kb * 32);
    f32x4 a0 = __builtin_nontemporal_load(ap);
    f32x4 a1 = __builtin_nontemporal_load(ap + 1);

#pragma unroll 2
    while (kb < kend) {
        int kn = kb + 4;
        int kc = (kn < KB_MAIN - 1) ? kn : (KB_MAIN - 1);   // clamped, in-bounds
        const f32x4* apn = (const f32x4*)(xrow + kc * 32);
        f32x4 p0 = __builtin_nontemporal_load(apn);
        f32x4 p1 = __builtin_nontemporal_load(apn + 1);

        const unsigned short* bb = Wb_g + (size_t)kb * 2048 + lane * 8;
        bf16x8 b0 = *(const bf16x8*)(bb);
        bf16x8 b1 = *(const bf16x8*)(bb + 512);
        bf16x8 b2 = *(const bf16x8*)(bb + 1024);
        bf16x8 b3 = *(const bf16x8*)(bb + 1536);
        bf16x8 af = to_bf16x8(a0, a1);
        acc[0] = __builtin_amdgcn_mfma_f32_16x16x32_bf16(af, b0, acc[0], 0, 0, 0);
        acc[1] = __builtin_amdgcn_mfma_f32_16x16x32_bf16(af, b1, acc[1], 0, 0, 0);
        acc[2] = __builtin_amdgcn_mfma_f32_16x16x32_bf16(af, b2, acc[2], 0, 0, 0);
        acc[3] = __builtin_amdgcn_mfma_f32_16x16x32_bf16(af, b3, acc[3], 0, 0, 0);

        a0 = p0; a1 = p1; kb = kn;
    }

    // Seed tail (k = 3200..3214) on exactly one wave of one K-half block.
    if (kh == 1 && wave == 3) {
        const float* srow = seeds + (size_t)arow * SEED_K;
        f32x4 s0 = {0.f, 0.f, 0.f, 0.f}, s1 = {0.f, 0.f, 0.f, 0.f};
#pragma unroll
        for (int j = 0; j < 4; ++j) {
            int c = quad * 8 + j;
            if (c < SEED_K) s0[j] = srow[c];
            if (c + 4 < SEED_K) s1[j] = srow[c + 4];
        }
        bf16x8 af = to_bf16x8(s0, s1);
        const unsigned short* bb = Wb_g + (size_t)KB_MAIN * 2048 + lane * 8;
        bf16x8 b0 = *(const bf16x8*)(bb);
        bf16x8 b1 = *(const bf16x8*)(bb + 512);
        bf16x8 b2 = *(const bf16x8*)(bb + 1024);
        bf16x8 b3 = *(const bf16x8*)(bb + 1536);
        acc[0] = __builtin_amdgcn_mfma_f32_16x16x32_bf16(af, b0, acc[0], 0, 0, 0);
        acc[1] = __builtin_amdgcn_mfma_f32_16x16x32_bf16(af, b1, acc[1], 0, 0, 0);
        acc[2] = __builtin_amdgcn_mfma_f32_16x16x32_bf16(af, b2, acc[2], 0, 0, 0);
        acc[3] = __builtin_amdgcn_mfma_f32_16x16x32_bf16(af, b3, acc[3], 0, 0, 0);
    }

    // Combine the 4 wave partials through LDS (stride 68: free 2-way aliasing).
    __shared__ float red[3][16][68];
    if (wave != 0) {
#pragma unroll
        for (int nt = 0; nt < 4; ++nt)
#pragma unroll
            for (int r = 0; r < 4; ++r)
                red[wave - 1][quad * 4 + r][nt * 16 + l15] = acc[nt][r];
    }
    __syncthreads();

    // Wave 0 stores this K-half's partial. C/D: col = lane&15, row = quad*4+r.
    if (wave == 0) {
        float* pdst = part + (size_t)kh * PART_N;
#pragma unroll
        for (int nt = 0; nt < 4; ++nt) {
            int j = nt * 16 + l15;
            if (j < NCOL) {
#pragma unroll
                for (int r = 0; r < 4; ++r) {
                    int m = quad * 4 + r;
                    float v = acc[nt][r] + red[0][m][j] + red[1][m][j] + red[2][m][j];
                    pdst[(size_t)(row_base + m) * NCOL + j] = v;
                }
            }
        }
    }
}

// out = part0 + part1 + bias.  245760 float4s, one per thread, 960 blocks.
__global__ __launch_bounds__(256) void combine(
    const float* __restrict__ part, float* __restrict__ out) {
    int idx = blockIdx.x * 256 + threadIdx.x;
    int fl  = idx * 4;
    f32x4 p0 = *(const f32x4*)(part + fl);
    f32x4 p1 = *(const f32x4*)(part + PART_N + fl);
    int jb = fl % NCOL;                       // multiple of 4 (60 % 4 == 0)
    f32x4 bv = *(const f32x4*)(bias_g + jb);
    f32x4 o = p0 + p1 + bv;
    *(f32x4*)(out + fl) = o;
}

extern "C" void kernel_launch(void* const* d_in, const int* in_sizes, int n_in,
                              void* d_out, int out_size, void* d_ws, size_t ws_size,
                              hipStream_t stream) {
    const float* x     = (const float*)d_in[0];
    const float* seeds = (const float*)d_in[1];
    const float* W     = (const float*)d_in[2];
    const float* b     = (const float*)d_in[3];
    float* out  = (float*)d_out;
    float* part = (float*)d_ws;

    prep_B<<<(WB_ELEMS + 255) / 256, 256, 0, stream>>>(W, b);
    gen_nodes_part<<<2048, 256, 0, stream>>>(x, seeds, part);
    combine<<<PART_N / 4 / 256, 256, 0, stream>>>(part, out);
}

// Round 3
// 307.802 us; speedup vs baseline: 1.0089x; 1.0089x over previous
//
#include <hip/hip_runtime.h>

// GenerateNodes: out[n,t,o,k] = sum_c mix[n,t,c] * W[k,o,c] + b[k,o]
// mix = concat(x [16384,3200], seeds [16384,15])  -> GEMM M=16384, K=3215, Ncol=60
// bf16 MFMA 16x16x32, B prepacked to fragment order in static __device__ mem.
// Key change this round: 32 rows per block (2 A-tiles per wave sharing one set
// of B-fragments) -> B-fragment L2 traffic halves (410 -> 205 MB); total CU
// vmem bytes 620 -> 415 MB. Grid 1024 blocks = 512 row-groups x 2 K-halves,
// 16 waves/CU at launch_bounds(256,4). Partials to d_ws (poison fill is
// unconditional, so using d_ws is free), tiny combine kernel adds bias.

#define NROWS    16384
#define CIN      3200
#define SEED_K   15
#define LIN_IN   3215
#define NCOL     60
#define KB_MAIN  100          // 3200 / 32
#define KB_TOT   101          // + tail block covering the 15 seed channels
#define WB_ELEMS (KB_TOT * 4 * 64 * 8)   // 206848 ushorts
#define PART_N   (NROWS * NCOL)          // 983040 floats per K-half partial

typedef __attribute__((ext_vector_type(8))) __bf16 bf16x8;
typedef __attribute__((ext_vector_type(4))) float f32x4;
typedef __attribute__((ext_vector_type(8))) unsigned short ushort8;

__device__ unsigned short Wb_g[WB_ELEMS];
__device__ __align__(16) float bias_g[64];

__device__ inline unsigned short f2bf_rne(float f) {
    unsigned int u = __builtin_bit_cast(unsigned int, f);
    u += 0x7fffu + ((u >> 16) & 1u);
    return (unsigned short)(u >> 16);
}

__device__ inline bf16x8 to_bf16x8(f32x4 a0, f32x4 a1) {
    ushort8 u;
    u[0] = f2bf_rne(a0[0]); u[1] = f2bf_rne(a0[1]);
    u[2] = f2bf_rne(a0[2]); u[3] = f2bf_rne(a0[3]);
    u[4] = f2bf_rne(a1[0]); u[5] = f2bf_rne(a1[1]);
    u[6] = f2bf_rne(a1[2]); u[7] = f2bf_rne(a1[3]);
    return __builtin_bit_cast(bf16x8, u);
}

// Pack W[20,3,3215] fp32 into bf16 B-fragment order:
// Wb[kb][nt][lane][jj] = B[k = kb*32 + (lane>>4)*8 + jj][n = nt*16 + (lane&15)]
// where B[c][j] = W[j%20][j/20][c]; zero-pad k>=3215 and n>=60.
// Also stages the transposed bias vector bias_g[j] = b[j%20][j/20].
__global__ void prep_B(const float* __restrict__ W, const float* __restrict__ b) {
    int idx = blockIdx.x * blockDim.x + threadIdx.x;
    if (idx >= WB_ELEMS) return;
    if (idx < 64) bias_g[idx] = (idx < NCOL) ? b[(idx % 20) * 3 + (idx / 20)] : 0.f;
    int jj   = idx & 7;
    int lane = (idx >> 3) & 63;
    int nt   = (idx >> 9) & 3;
    int kb   = idx >> 11;
    int k = kb * 32 + (lane >> 4) * 8 + jj;
    int n = nt * 16 + (lane & 15);
    float v = 0.0f;
    if (k < LIN_IN && n < NCOL) {
        int o = n / 20, kn = n % 20;
        v = W[(kn * 3 + o) * LIN_IN + k];
    }
    Wb_g[idx] = f2bf_rne(v);
}

__global__ __launch_bounds__(256, 4) void gen_nodes_part(
    const float* __restrict__ x, const float* __restrict__ seeds,
    float* __restrict__ part) {
    const int lane = threadIdx.x & 63;
    const int wave = threadIdx.x >> 6;
    const int quad = lane >> 4;
    const int l15  = lane & 15;
    const int rg   = blockIdx.x >> 1;       // 32-row group, 0..511
    const int kh   = blockIdx.x & 1;        // K half, 0..1
    const int row_base = rg * 32;
    const int arow = row_base + l15;        // tile-0 row; tile-1 row = +16

    const float* xrow0 = x + (size_t)arow * CIN + quad * 8;
    const float* xrow1 = xrow0 + (size_t)16 * CIN;

    f32x4 acc[2][4];
#pragma unroll
    for (int t = 0; t < 2; ++t)
#pragma unroll
        for (int i = 0; i < 4; ++i) acc[t][i] = (f32x4){0.f, 0.f, 0.f, 0.f};

    // This wave does kb = kh*50 + wave, +4, +8, ... (< kh*50+50).
    // Two A-tiles share each B-fragment load. Depth-2 rotated prefetch.
    const int kend = kh * 50 + 50;
    int kb = kh * 50 + wave;
    {
        const f32x4* ap0 = (const f32x4*)(xrow0 + kb * 32);
        const f32x4* ap1 = (const f32x4*)(xrow1 + kb * 32);
        f32x4 a0 = __builtin_nontemporal_load(ap0);
        f32x4 a1 = __builtin_nontemporal_load(ap0 + 1);
        f32x4 a2 = __builtin_nontemporal_load(ap1);
        f32x4 a3 = __builtin_nontemporal_load(ap1 + 1);

#pragma unroll 2
        while (kb < kend) {
            int kn = kb + 4;
            int kc = (kn < KB_MAIN - 1) ? kn : (KB_MAIN - 1);   // clamped, in-bounds
            const f32x4* apn0 = (const f32x4*)(xrow0 + kc * 32);
            const f32x4* apn1 = (const f32x4*)(xrow1 + kc * 32);
            f32x4 p0 = __builtin_nontemporal_load(apn0);
            f32x4 p1 = __builtin_nontemporal_load(apn0 + 1);
            f32x4 p2 = __builtin_nontemporal_load(apn1);
            f32x4 p3 = __builtin_nontemporal_load(apn1 + 1);

            const unsigned short* bb = Wb_g + (size_t)kb * 2048 + lane * 8;
            bf16x8 b0 = *(const bf16x8*)(bb);
            bf16x8 b1 = *(const bf16x8*)(bb + 512);
            bf16x8 b2 = *(const bf16x8*)(bb + 1024);
            bf16x8 b3 = *(const bf16x8*)(bb + 1536);
            bf16x8 af0 = to_bf16x8(a0, a1);
            bf16x8 af1 = to_bf16x8(a2, a3);
            acc[0][0] = __builtin_amdgcn_mfma_f32_16x16x32_bf16(af0, b0, acc[0][0], 0, 0, 0);
            acc[0][1] = __builtin_amdgcn_mfma_f32_16x16x32_bf16(af0, b1, acc[0][1], 0, 0, 0);
            acc[0][2] = __builtin_amdgcn_mfma_f32_16x16x32_bf16(af0, b2, acc[0][2], 0, 0, 0);
            acc[0][3] = __builtin_amdgcn_mfma_f32_16x16x32_bf16(af0, b3, acc[0][3], 0, 0, 0);
            acc[1][0] = __builtin_amdgcn_mfma_f32_16x16x32_bf16(af1, b0, acc[1][0], 0, 0, 0);
            acc[1][1] = __builtin_amdgcn_mfma_f32_16x16x32_bf16(af1, b1, acc[1][1], 0, 0, 0);
            acc[1][2] = __builtin_amdgcn_mfma_f32_16x16x32_bf16(af1, b2, acc[1][2], 0, 0, 0);
            acc[1][3] = __builtin_amdgcn_mfma_f32_16x16x32_bf16(af1, b3, acc[1][3], 0, 0, 0);

            a0 = p0; a1 = p1; a2 = p2; a3 = p3; kb = kn;
        }
    }

    // Seed tail (k = 3200..3214) on exactly one wave of one K-half block.
    if (kh == 1 && wave == 3) {
        const unsigned short* bb = Wb_g + (size_t)KB_MAIN * 2048 + lane * 8;
        bf16x8 b0 = *(const bf16x8*)(bb);
        bf16x8 b1 = *(const bf16x8*)(bb + 512);
        bf16x8 b2 = *(const bf16x8*)(bb + 1024);
        bf16x8 b3 = *(const bf16x8*)(bb + 1536);
#pragma unroll
        for (int t = 0; t < 2; ++t) {
            const float* srow = seeds + (size_t)(arow + t * 16) * SEED_K;
            f32x4 s0 = {0.f, 0.f, 0.f, 0.f}, s1 = {0.f, 0.f, 0.f, 0.f};
#pragma unroll
            for (int j = 0; j < 4; ++j) {
                int c = quad * 8 + j;
                if (c < SEED_K) s0[j] = srow[c];
                if (c + 4 < SEED_K) s1[j] = srow[c + 4];
            }
            bf16x8 af = to_bf16x8(s0, s1);
            acc[t][0] = __builtin_amdgcn_mfma_f32_16x16x32_bf16(af, b0, acc[t][0], 0, 0, 0);
            acc[t][1] = __builtin_amdgcn_mfma_f32_16x16x32_bf16(af, b1, acc[t][1], 0, 0, 0);
            acc[t][2] = __builtin_amdgcn_mfma_f32_16x16x32_bf16(af, b2, acc[t][2], 0, 0, 0);
            acc[t][3] = __builtin_amdgcn_mfma_f32_16x16x32_bf16(af, b3, acc[t][3], 0, 0, 0);
        }
    }

    // Combine the 4 wave partials through LDS (stride 68: free 2-way aliasing).
    __shared__ float red[3][32][68];
    if (wave != 0) {
#pragma unroll
        for (int t = 0; t < 2; ++t)
#pragma unroll
            for (int nt = 0; nt < 4; ++nt)
#pragma unroll
                for (int r = 0; r < 4; ++r)
                    red[wave - 1][t * 16 + quad * 4 + r][nt * 16 + l15] = acc[t][nt][r];
    }
    __syncthreads();

    // Wave 0 stores this K-half's partial. C/D: col = lane&15, row = quad*4+r.
    if (wave == 0) {
        float* pdst = part + (size_t)kh * PART_N;
#pragma unroll
        for (int t = 0; t < 2; ++t) {
#pragma unroll
            for (int nt = 0; nt < 4; ++nt) {
                int j = nt * 16 + l15;
                if (j < NCOL) {
#pragma unroll
                    for (int r = 0; r < 4; ++r) {
                        int m = t * 16 + quad * 4 + r;
                        float v = acc[t][nt][r] + red[0][m][j] + red[1][m][j] + red[2][m][j];
                        pdst[(size_t)(row_base + m) * NCOL + j] = v;
                    }
                }
            }
        }
    }
}

// out = part0 + part1 + bias.  245760 float4s, one per thread, 960 blocks.
__global__ __launch_bounds__(256) void combine(
    const float* __restrict__ part, float* __restrict__ out) {
    int idx = blockIdx.x * 256 + threadIdx.x;
    int fl  = idx * 4;
    f32x4 p0 = *(const f32x4*)(part + fl);
    f32x4 p1 = *(const f32x4*)(part + PART_N + fl);
    int jb = fl % NCOL;                       // multiple of 4 (60 % 4 == 0)
    f32x4 bv = *(const f32x4*)(bias_g + jb);
    f32x4 o = p0 + p1 + bv;
    *(f32x4*)(out + fl) = o;
}

extern "C" void kernel_launch(void* const* d_in, const int* in_sizes, int n_in,
                              void* d_out, int out_size, void* d_ws, size_t ws_size,
                              hipStream_t stream) {
    const float* x     = (const float*)d_in[0];
    const float* seeds = (const float*)d_in[1];
    const float* W     = (const float*)d_in[2];
    const float* b     = (const float*)d_in[3];
    float* out  = (float*)d_out;
    float* part = (float*)d_ws;

    prep_B<<<(WB_ELEMS + 255) / 256, 256, 0, stream>>>(W, b);
    gen_nodes_part<<<1024, 256, 0, stream>>>(x, seeds, part);
    combine<<<PART_N / 4 / 256, 256, 0, stream>>>(part, out);
}

// Round 4
// 297.990 us; speedup vs baseline: 1.0422x; 1.0329x over previous
//
#include <hip/hip_runtime.h>

// GenerateNodes: out[n,t,o,k] = sum_c mix[n,t,c] * W[k,o,c] + b[k,o]
// mix = concat(x [16384,3200], seeds [16384,15])  -> GEMM M=16384, K=3215, Ncol=60
// Round 4: fix the MLP ceiling. All prior variants buffered A in VGPRs
// (~1 KB in flight/CU -> ~4 TB/s). Now A and B are staged to LDS with
// __builtin_amdgcn_global_load_lds (width 16): LDS-destined loads hold no
// VGPRs, so each block keeps a whole 16 KB chunk in flight (need ~9 KB/CU
// for 6.3 TB/s). 512 blocks x 32 rows, 4 waves = 2 row-tiles x 2 col-halves,
// double-buffered 2-kb chunks (32 KB LDS, 2+ blocks/CU so one block's
// vmcnt(0) barrier drain overlaps the other's issue). Single GEMM kernel
// writes out + bias directly (combine kernel and d_ws partials removed).

#define NROWS    16384
#define CIN      3200
#define SEED_K   15
#define LIN_IN   3215
#define NCOL     60
#define KB_MAIN  100          // 3200 / 32
#define KB_TOT   101          // + tail block covering the 15 seed channels
#define WB_ELEMS (KB_TOT * 4 * 64 * 8)   // 206848 ushorts
#define CHUNK_KB 2            // kb-blocks staged per pipeline step
#define NCHUNKS  50           // 100 / 2
#define A_BYTES  1024         // one (kb,wt,h) A slice: 64 lanes x 16 B
#define B_BASE   16384        // B region offset in smem
#define SMEM_SZ  32768        // A: 2buf*2kb*2wt*2h KB=16K, B: 2buf*2kb*4nt KB=16K

typedef __attribute__((ext_vector_type(8))) __bf16 bf16x8;
typedef __attribute__((ext_vector_type(4))) float f32x4;
typedef __attribute__((ext_vector_type(8))) unsigned short ushort8;

__device__ unsigned short Wb_g[WB_ELEMS];
__device__ __align__(16) float bias_g[64];

__device__ inline unsigned short f2bf_rne(float f) {
    unsigned int u = __builtin_bit_cast(unsigned int, f);
    u += 0x7fffu + ((u >> 16) & 1u);
    return (unsigned short)(u >> 16);
}

__device__ inline bf16x8 to_bf16x8(f32x4 a0, f32x4 a1) {
    ushort8 u;
    u[0] = f2bf_rne(a0[0]); u[1] = f2bf_rne(a0[1]);
    u[2] = f2bf_rne(a0[2]); u[3] = f2bf_rne(a0[3]);
    u[4] = f2bf_rne(a1[0]); u[5] = f2bf_rne(a1[1]);
    u[6] = f2bf_rne(a1[2]); u[7] = f2bf_rne(a1[2 + 1]);
    return __builtin_bit_cast(bf16x8, u);
}

// global -> LDS direct (16 B per lane; dest = uniform base + lane*16).
typedef __attribute__((address_space(3))) void lds_void;
typedef __attribute__((address_space(1))) const void gm_void;
__device__ __forceinline__ void gll16(const void* g, void* l) {
    __builtin_amdgcn_global_load_lds((gm_void*)g, (lds_void*)l, 16, 0, 0);
}

// Pack W[20,3,3215] fp32 into bf16 B-fragment order:
// Wb[kb][nt][lane][jj] = B[k = kb*32 + (lane>>4)*8 + jj][n = nt*16 + (lane&15)]
// where B[c][j] = W[j%20][j/20][c]; zero-pad k>=3215 and n>=60.
// Also stages the transposed bias vector bias_g[j] = b[j%20][j/20].
__global__ void prep_B(const float* __restrict__ W, const float* __restrict__ b) {
    int idx = blockIdx.x * blockDim.x + threadIdx.x;
    if (idx >= WB_ELEMS) return;
    if (idx < 64) bias_g[idx] = (idx < NCOL) ? b[(idx % 20) * 3 + (idx / 20)] : 0.f;
    int jj   = idx & 7;
    int lane = (idx >> 3) & 63;
    int nt   = (idx >> 9) & 3;
    int kb   = idx >> 11;
    int k = kb * 32 + (lane >> 4) * 8 + jj;
    int n = nt * 16 + (lane & 15);
    float v = 0.0f;
    if (k < LIN_IN && n < NCOL) {
        int o = n / 20, kn = n % 20;
        v = W[(kn * 3 + o) * LIN_IN + k];
    }
    Wb_g[idx] = f2bf_rne(v);
}

__global__ __launch_bounds__(256) void gen_nodes(
    const float* __restrict__ x, const float* __restrict__ seeds,
    float* __restrict__ out) {
    const int lane = threadIdx.x & 63;
    const int wave = threadIdx.x >> 6;
    const int quad = lane >> 4;
    const int l15  = lane & 15;
    const int rb0  = blockIdx.x * 32;       // 32 rows per block
    const int wt   = wave & 1;              // row-tile (16 rows)
    const int nh   = wave >> 1;             // col-half (nt pair)

    __shared__ __align__(16) char smem[SMEM_SZ];

    // Per-lane A source: row = rb0 + (wt)*16 + l15, col floats = cbk*32 + quad*8 + h*4
    const float* xlane = x + (size_t)(rb0 + l15) * CIN + quad * 8;

    f32x4 acc[2];
    acc[0] = (f32x4){0.f, 0.f, 0.f, 0.f};
    acc[1] = (f32x4){0.f, 0.f, 0.f, 0.f};

    // ---- staging: 16 loads per chunk, 4 per wave -------------------------
    // wave 0: A of kb=0 (wt0h0, wt0h1, wt1h0, wt1h1); wave 1: A of kb=1;
    // wave 2: B of kb=0 (nt 0..3);                    wave 3: B of kb=1.
    auto stage = [&](int c, int buf) {
        if (wave < 2) {
            const int kb  = wave;
            const int cbk = c * CHUNK_KB + kb;
            const float* s0 = xlane + (size_t)cbk * 32;
            char* ab = smem + ((buf * 2 + kb) * 4) * A_BYTES;
            gll16(s0,                ab);
            gll16(s0 + 4,            ab + 1024);
            gll16(s0 + 16 * CIN,     ab + 2048);
            gll16(s0 + 16 * CIN + 4, ab + 3072);
        } else {
            const int kb  = wave - 2;
            const int cbk = c * CHUNK_KB + kb;
            const unsigned short* s = Wb_g + (size_t)cbk * 2048 + lane * 8;
            char* bb = smem + B_BASE + ((buf * 2 + kb) * 4) * A_BYTES;
            gll16(s,        bb);
            gll16(s + 512,  bb + 1024);
            gll16(s + 1024, bb + 2048);
            gll16(s + 1536, bb + 3072);
        }
    };

    stage(0, 0);
    __syncthreads();                         // drains vmcnt -> buf0 ready

    for (int c = 0; c < NCHUNKS; ++c) {
        const int buf = c & 1;
        if (c + 1 < NCHUNKS) stage(c + 1, buf ^ 1);

#pragma unroll
        for (int kb = 0; kb < CHUNK_KB; ++kb) {
            const char* ab = smem + (((buf * 2 + kb) * 2 + wt) * 2) * A_BYTES + lane * 16;
            f32x4 a0 = *(const f32x4*)(ab);
            f32x4 a1 = *(const f32x4*)(ab + 1024);
            const char* bb = smem + B_BASE + ((buf * 2 + kb) * 4 + nh * 2) * A_BYTES + lane * 16;
            bf16x8 b0 = *(const bf16x8*)(bb);
            bf16x8 b1 = *(const bf16x8*)(bb + 1024);
            bf16x8 af = to_bf16x8(a0, a1);
            acc[0] = __builtin_amdgcn_mfma_f32_16x16x32_bf16(af, b0, acc[0], 0, 0, 0);
            acc[1] = __builtin_amdgcn_mfma_f32_16x16x32_bf16(af, b1, acc[1], 0, 0, 0);
        }
        __syncthreads();                     // drains vmcnt -> next buf ready
    }

    // Seed tail (k = 3200..3214), kb index 100, B from global (L2-hot).
    {
        const float* srow = seeds + (size_t)(rb0 + wt * 16 + l15) * SEED_K;
        f32x4 s0 = {0.f, 0.f, 0.f, 0.f}, s1 = {0.f, 0.f, 0.f, 0.f};
#pragma unroll
        for (int j = 0; j < 4; ++j) {
            int cc = quad * 8 + j;
            if (cc < SEED_K) s0[j] = srow[cc];
            if (cc + 4 < SEED_K) s1[j] = srow[cc + 4];
        }
        bf16x8 af = to_bf16x8(s0, s1);
        const unsigned short* bb = Wb_g + (size_t)KB_MAIN * 2048 + lane * 8;
        bf16x8 b0 = *(const bf16x8*)(bb + nh * 1024);
        bf16x8 b1 = *(const bf16x8*)(bb + nh * 1024 + 512);
        acc[0] = __builtin_amdgcn_mfma_f32_16x16x32_bf16(af, b0, acc[0], 0, 0, 0);
        acc[1] = __builtin_amdgcn_mfma_f32_16x16x32_bf16(af, b1, acc[1], 0, 0, 0);
    }

    // Epilogue: C/D layout col = lane&15, row = quad*4 + reg. j = nt*16 + col.
#pragma unroll
    for (int t = 0; t < 2; ++t) {
        int j = (nh * 2 + t) * 16 + l15;
        if (j < NCOL) {
            float bias = bias_g[j];
#pragma unroll
            for (int r = 0; r < 4; ++r) {
                int m = wt * 16 + quad * 4 + r;
                out[(size_t)(rb0 + m) * NCOL + j] = acc[t][r] + bias;
            }
        }
    }
}

extern "C" void kernel_launch(void* const* d_in, const int* in_sizes, int n_in,
                              void* d_out, int out_size, void* d_ws, size_t ws_size,
                              hipStream_t stream) {
    const float* x     = (const float*)d_in[0];
    const float* seeds = (const float*)d_in[1];
    const float* W     = (const float*)d_in[2];
    const float* b     = (const float*)d_in[3];
    float* out = (float*)d_out;
    (void)d_ws; (void)ws_size;

    prep_B<<<(WB_ELEMS + 255) / 256, 256, 0, stream>>>(W, b);
    gen_nodes<<<NROWS / 32, 256, 0, stream>>>(x, seeds, out);
}